// Round 2
// baseline (440.984 us; speedup 1.0000x reference)
//
#include <hip/hip_runtime.h>

// 3D Haar DWT, x: (2,32,64,128,128) float32 -> 8 subbands (2,32,32,64,64) float32,
// concatenated in order LLL,LLH,LHL,LHH,HLL,HLH,HHL,HHH (letter order = D,H,W axis).
// Every output voxel = signed sum of one 2x2x2 input block * (1/sqrt(2))^3.
// One thread handles 4 consecutive output q's (8 input w's) for fixed (n,c,r,p):
//   8 float4 loads (4 rows x 32B), 8 float4 stores (one per subband).

namespace {
constexpr long SUBBAND = 2L * 32 * 32 * 64 * 64;     // 4,194,304 elements per subband
constexpr int TOTAL_THREADS = 2 * 32 * 32 * 64 * 16; // n*c*r*p*(q-groups of 4)
}

__global__ __launch_bounds__(256) void dwt3d_haar_f32_kernel(
    const float* __restrict__ x, float* __restrict__ out)
{
    int idx = blockIdx.x * blockDim.x + threadIdx.x;
    int qg = idx & 15;          // q-group: q = 4*qg .. 4*qg+3  (w = 8*qg .. 8*qg+7)
    int p  = (idx >> 4) & 63;   // output h index
    int r  = (idx >> 10) & 31;  // output d index
    int nc = idx >> 15;         // n*32 + c, [0,64)

    // input layout: (((nc*64 + d)*128 + h)*128 + w); d = 2r(+1), h = 2p(+1)
    const float* px = x + ((((long)nc * 64 + 2 * r) * 128 + 2 * p) * 128 + 8 * qg);

    float A[8], B[8], C[8], D[8];
    ((float4*)A)[0] = *(const float4*)(px);                 // d0 h0 w[0:4]
    ((float4*)A)[1] = *(const float4*)(px + 4);             // d0 h0 w[4:8]
    ((float4*)B)[0] = *(const float4*)(px + 128);           // d0 h1
    ((float4*)B)[1] = *(const float4*)(px + 132);
    ((float4*)C)[0] = *(const float4*)(px + 16384);         // d1 h0
    ((float4*)C)[1] = *(const float4*)(px + 16388);
    ((float4*)D)[0] = *(const float4*)(px + 16384 + 128);   // d1 h1
    ((float4*)D)[1] = *(const float4*)(px + 16384 + 132);

    float ov[8][4];
    const float K = 0.35355339059327373f; // (1/sqrt(2))^3

#pragma unroll
    for (int j = 0; j < 4; ++j) {
        float a0 = A[2*j], a1 = A[2*j+1];
        float b0 = B[2*j], b1 = B[2*j+1];
        float c0 = C[2*j], c1 = C[2*j+1];
        float d0 = D[2*j], d1 = D[2*j+1];
        // W stage: sum/diff of w-pair per (d,h) row
        float sa = a0 + a1, da = a0 - a1; // d0 h0
        float sb = b0 + b1, db = b0 - b1; // d0 h1
        float sc = c0 + c1, dc = c0 - c1; // d1 h0
        float se = d0 + d1, de = d0 - d1; // d1 h1
        // H stage: low = h0+h1, high = h0-h1
        float sLs = sa + sb, sHs = sa - sb;  // d0, w-low
        float sLd = da + db, sHd = da - db;  // d0, w-high
        float tLs = sc + se, tHs = sc - se;  // d1, w-low
        float tLd = dc + de, tHd = dc - de;  // d1, w-high
        // D stage: low = d0+d1, high = d0-d1. Subband s bits: (D,H,W) = (s>>2, s>>1&1, s&1)
        ov[0][j] = K * (sLs + tLs); // LLL
        ov[1][j] = K * (sLd + tLd); // LLH
        ov[2][j] = K * (sHs + tHs); // LHL
        ov[3][j] = K * (sHd + tHd); // LHH
        ov[4][j] = K * (sLs - tLs); // HLL
        ov[5][j] = K * (sLd - tLd); // HLH
        ov[6][j] = K * (sHs - tHs); // HHL
        ov[7][j] = K * (sHd - tHd); // HHH
    }

    // output: s*SUBBAND + (((nc*32 + r)*64 + p)*64 + q)
    long obase = (((long)nc * 32 + r) * 64 + p) * 64 + 4 * qg;
#pragma unroll
    for (int s = 0; s < 8; ++s) {
        *(float4*)(out + s * SUBBAND + obase) =
            make_float4(ov[s][0], ov[s][1], ov[s][2], ov[s][3]);
    }
}

extern "C" void kernel_launch(void* const* d_in, const int* in_sizes, int n_in,
                              void* d_out, int out_size, void* d_ws, size_t ws_size,
                              hipStream_t stream) {
    const float* x = (const float*)d_in[0];  // (2,32,64,128,128) f32
    float* out = (float*)d_out;              // 8 subbands concatenated, f32
    dwt3d_haar_f32_kernel<<<TOTAL_THREADS / 256, 256, 0, stream>>>(x, out);
}

// Round 3
// 439.138 us; speedup vs baseline: 1.0042x; 1.0042x over previous
//
#include <hip/hip_runtime.h>

// 3D Haar DWT, x: (2,32,64,128,128) f32 -> 8 subbands (2,32,32,64,64) f32,
// order LLL,LLH,LHL,LHH,HLL,HLH,HHL,HHH (letters = D,H,W; L=sum, H=diff, *K).
// Pure streaming: 134 MB in, 134 MB out, zero reuse -> nontemporal loads/stores.
// One thread: 4 output q's for fixed (n,c,r,p): 8x16B nt-loads, 8x16B nt-stores.

typedef float f32x4 __attribute__((ext_vector_type(4)));

namespace {
constexpr int SUBBAND = 2 * 32 * 32 * 64 * 64;       // 4,194,304 elems (fits int32)
constexpr int TOTAL_THREADS = 2 * 32 * 32 * 64 * 16; // n*c*r*p*(q-groups of 4)
}

__global__ __launch_bounds__(256) void dwt3d_haar_f32_nt(
    const float* __restrict__ x, float* __restrict__ out)
{
    int idx = blockIdx.x * blockDim.x + threadIdx.x;
    int qg = idx & 15;          // q = 4*qg .. 4*qg+3  (w = 8*qg .. 8*qg+7)
    int p  = (idx >> 4) & 63;   // output h
    int r  = (idx >> 10) & 31;  // output d
    int nc = idx >> 15;         // n*32 + c, [0,64)

    // input: (((nc*64 + d)*128 + h)*128 + w); d=2r(+1), h=2p(+1). Max offset 2^27 elems.
    const float* px = x + (((nc * 64 + 2 * r) * 128 + 2 * p) * 128 + 8 * qg);

    f32x4 A0 = __builtin_nontemporal_load((const f32x4*)(px));                 // d0 h0 w0..3
    f32x4 A1 = __builtin_nontemporal_load((const f32x4*)(px + 4));             // d0 h0 w4..7
    f32x4 B0 = __builtin_nontemporal_load((const f32x4*)(px + 128));           // d0 h1
    f32x4 B1 = __builtin_nontemporal_load((const f32x4*)(px + 132));
    f32x4 C0 = __builtin_nontemporal_load((const f32x4*)(px + 16384));         // d1 h0
    f32x4 C1 = __builtin_nontemporal_load((const f32x4*)(px + 16388));
    f32x4 D0 = __builtin_nontemporal_load((const f32x4*)(px + 16384 + 128));   // d1 h1
    f32x4 D1 = __builtin_nontemporal_load((const f32x4*)(px + 16384 + 132));

    // W stage: even/odd deinterleave across the 8 w's -> 4 q lanes, then sum/diff.
    f32x4 ae = __builtin_shufflevector(A0, A1, 0, 2, 4, 6);
    f32x4 ao = __builtin_shufflevector(A0, A1, 1, 3, 5, 7);
    f32x4 be = __builtin_shufflevector(B0, B1, 0, 2, 4, 6);
    f32x4 bo = __builtin_shufflevector(B0, B1, 1, 3, 5, 7);
    f32x4 ce = __builtin_shufflevector(C0, C1, 0, 2, 4, 6);
    f32x4 co = __builtin_shufflevector(C0, C1, 1, 3, 5, 7);
    f32x4 de = __builtin_shufflevector(D0, D1, 0, 2, 4, 6);
    f32x4 do_ = __builtin_shufflevector(D0, D1, 1, 3, 5, 7);

    f32x4 sa = ae + ao, da = ae - ao;   // d0 h0
    f32x4 sb = be + bo, db = be - bo;   // d0 h1
    f32x4 sc = ce + co, dc = ce - co;   // d1 h0
    f32x4 sd = de + do_, dd = de - do_; // d1 h1

    // H stage
    f32x4 sLs = sa + sb, sHs = sa - sb; // d0 w-low
    f32x4 sLd = da + db, sHd = da - db; // d0 w-high
    f32x4 tLs = sc + sd, tHs = sc - sd; // d1 w-low
    f32x4 tLd = dc + dd, tHd = dc - dd; // d1 w-high

    const float K = 0.35355339059327373f; // (1/sqrt(2))^3
    // out: s*SUBBAND + (((nc*32 + r)*64 + p)*64 + q); max s*SUBBAND+... = 2^25 elems, int ok
    float* po = out + (((nc * 32 + r) * 64 + p) * 64 + 4 * qg);

    // D stage + scale; subband bits (D,H,W) = (s>>2, s>>1&1, s&1)
    __builtin_nontemporal_store(K * (sLs + tLs), (f32x4*)(po + 0 * SUBBAND)); // LLL
    __builtin_nontemporal_store(K * (sLd + tLd), (f32x4*)(po + 1 * SUBBAND)); // LLH
    __builtin_nontemporal_store(K * (sHs + tHs), (f32x4*)(po + 2 * SUBBAND)); // LHL
    __builtin_nontemporal_store(K * (sHd + tHd), (f32x4*)(po + 3 * SUBBAND)); // LHH
    __builtin_nontemporal_store(K * (sLs - tLs), (f32x4*)(po + 4 * SUBBAND)); // HLL
    __builtin_nontemporal_store(K * (sLd - tLd), (f32x4*)(po + 5 * SUBBAND)); // HLH
    __builtin_nontemporal_store(K * (sHs - tHs), (f32x4*)(po + 6 * SUBBAND)); // HHL
    __builtin_nontemporal_store(K * (sHd - tHd), (f32x4*)(po + 7 * SUBBAND)); // HHH
}

extern "C" void kernel_launch(void* const* d_in, const int* in_sizes, int n_in,
                              void* d_out, int out_size, void* d_ws, size_t ws_size,
                              hipStream_t stream) {
    const float* x = (const float*)d_in[0];  // (2,32,64,128,128) f32
    float* out = (float*)d_out;              // 8 subbands concatenated, f32
    dwt3d_haar_f32_nt<<<TOTAL_THREADS / 256, 256, 0, stream>>>(x, out);
}